// Round 13
// baseline (368.901 us; speedup 1.0000x reference)
//
#include <hip/hip_runtime.h>
#include <math.h>

// SVPF step: B=8, N=2048, D=4, fp32.  3 SVGD iterations.
// log_weight output channel is exactly -log(2048) (log_post cancels).
//
// R13 == R12 resubmission (R12 bench failed on GPU acquisition; experiment
// unmeasured).  Changes vs R11 (diagnosis: session audit shows the SIMPLE
// R4-style grad/stein (16 lanes/particle, 2-way ILP, global reads, 1024
// blocks) measured ~13-17us each, while every multi-row "improvement" since
// (R6 2-row 60us, R7 4-row 40us, R11 LDS-dbuf 47us) was a 2-3x regression
// hidden by kernel fusion.  Many small desynchronized 16-lane groups hide
// latency better than explicit pipelines):
//  - grad (in s1) and stein (in s3) reverted to the R4 bodies verbatim.
//  - 10-launch skeleton, fused hist-scan/zeroing, hist kernels unchanged.
//
// ws layout (floats):
//   xA[65536] xB[65536] g[65536] step[65536] ap[65536]
//   state[16 ints] hist0[8*2048 ints] hist1[8*4096 ints]

#define NPART 2048
#define KRANK 2097151               // (2048*2048-1)/2, lower-median rank
#define LOGN_F 7.6246189861593985f  // log(2048)
#define A_C 0.9f

// ---------- init: x0 = A*prev + noise; ap = A*prev; zero hist0+hist1
__global__ __launch_bounds__(256) void k_init(const float* __restrict__ prev,
                                              const float* __restrict__ noise,
                                              float* __restrict__ x0,
                                              float* __restrict__ apb,
                                              int* __restrict__ hists) {
  int idx = blockIdx.x * 256 + threadIdx.x;   // 0..16383 (B*N)
  float4 p  = ((const float4*)prev)[idx];
  float4 nz = ((const float4*)noise)[idx];
  float4 ap = make_float4(A_C*p.x, A_C*p.y, A_C*p.z, A_C*p.w);
  ((float4*)x0)[idx]  = make_float4(ap.x+nz.x, ap.y+nz.y, ap.z+nz.z, ap.w+nz.w);
  ((float4*)apb)[idx] = ap;
  if (idx < 12288) ((int4*)hists)[idx] = make_int4(0, 0, 0, 0);  // 49152 ints
}

// ---------- S1: role = blockIdx&1.  role 0: grad (1024 blocks, R4 style).
// role 1: hist0 (1024 blocks).  Also zeroes hist1.
__global__ __launch_bounds__(256) void k_s1(const float* __restrict__ x,
                                            const float* __restrict__ apb,
                                            const float* __restrict__ obs,
                                            float* __restrict__ g,
                                            int* __restrict__ hist0,
                                            int* __restrict__ hist1) {
  if (threadIdx.x < 4)
    ((int4*)hist1)[blockIdx.x*4 + threadIdx.x] = make_int4(0, 0, 0, 0);
  int role = blockIdx.x & 1;
  int id   = blockIdx.x >> 1;

  if (role == 0) {
    // ---- grad, R4 style: 16 threads/particle, 16 particles/block ----
    int b   = id >> 7;                // 128 blocks/batch
    int ip  = threadIdx.x >> 4;
    int sub = threadIdx.x & 15;
    int i = (id & 127)*16 + ip;
    const float4* ab = (const float4*)apb + b*NPART;
    float4 xi = ((const float4*)x)[b*NPART + i];

    float sum1 = 0.f, sum2 = 0.f;
    float4 acc1 = make_float4(0.f,0.f,0.f,0.f);
    float4 acc2 = make_float4(0.f,0.f,0.f,0.f);
#pragma unroll 4
    for (int c = 0; c < 64; ++c) {
      int j = sub + 16*c;
      float4 a1 = ab[j];
      float4 a2 = ab[j + 1024];
      float dx1 = xi.x-a1.x, dy1 = xi.y-a1.y, dz1 = xi.z-a1.z, dw1 = xi.w-a1.w;
      float dx2 = xi.x-a2.x, dy2 = xi.y-a2.y, dz2 = xi.z-a2.z, dw2 = xi.w-a2.w;
      float e1 = __expf(-0.5f*(dx1*dx1 + dy1*dy1 + dz1*dz1 + dw1*dw1));
      float e2 = __expf(-0.5f*(dx2*dx2 + dy2*dy2 + dz2*dz2 + dw2*dw2));
      sum1 += e1; sum2 += e2;
      acc1.x += e1*a1.x; acc1.y += e1*a1.y; acc1.z += e1*a1.z; acc1.w += e1*a1.w;
      acc2.x += e2*a2.x; acc2.y += e2*a2.y; acc2.z += e2*a2.z; acc2.w += e2*a2.w;
    }
    float sum = sum1 + sum2;
    float4 acc = make_float4(acc1.x+acc2.x, acc1.y+acc2.y,
                             acc1.z+acc2.z, acc1.w+acc2.w);
#pragma unroll
    for (int d = 1; d < 16; d <<= 1) {
      sum   += __shfl_xor(sum, d);
      acc.x += __shfl_xor(acc.x, d);
      acc.y += __shfl_xor(acc.y, d);
      acc.z += __shfl_xor(acc.z, d);
      acc.w += __shfl_xor(acc.w, d);
    }
    if (sub == 0) {
      float inv = 1.0f / sum;
      float4 ob = ((const float4*)obs)[b];
      float4 gg;
      gg.x = acc.x*inv + ob.x - 2.0f*xi.x;
      gg.y = acc.y*inv + ob.y - 2.0f*xi.y;
      gg.z = acc.z*inv + ob.z - 2.0f*xi.z;
      gg.w = acc.w*inv + ob.w - 2.0f*xi.w;
      ((float4*)g)[b*NPART + i] = gg;
    }
  } else {
    // ---- hist0: LDS-staged, 2-copy histogram (unchanged) ----
    int b     = id >> 7;
    int sub2  = id & 127;
    int itile = sub2 >> 4;            // 8 i-tiles of 256
    int ktile = sub2 & 15;            // 16 k-tiles of 64
    __shared__ float4 sxi[256];
    __shared__ float4 sxw[320];
    __shared__ int    sh[2*2049];

    const float4* xb = (const float4*)x + b*NPART;
    int ibase = itile*256;
    int k0 = ktile*64 + 1;
    sxi[threadIdx.x] = xb[ibase + threadIdx.x];
    for (int t = threadIdx.x; t < 320; t += 256)
      sxw[t] = xb[(ibase + k0 + t) & (NPART - 1)];
    for (int t = threadIdx.x; t < 2*2049; t += 256) sh[t] = 0;
    __syncthreads();

    float4 xi = sxi[threadIdx.x];
    int cofs = (threadIdx.x & 1) * 2049;
#pragma unroll 4
    for (int kk = 0; kk < 64; ++kk) {
      int w = (ktile == 15 && kk == 63) ? 1 : 2;   // wave-uniform
      float4 xj = sxw[threadIdx.x + kk];
      float dx = xi.x - xj.x, dy = xi.y - xj.y;
      float dz = xi.z - xj.z, dw = xi.w - xj.w;
      float sq = dx*dx + dy*dy + dz*dz + dw*dw;    // >= 0
      atomicAdd(&sh[cofs + (__float_as_uint(sq) >> 20)], w);
    }
    __syncthreads();
    int* hb = hist0 + b*2048;
    for (int t = threadIdx.x; t < 2048; t += 256) {
      int c = sh[t] + sh[t + 2049];
      if (c) atomicAdd(&hb[t], c);
    }
  }
}

// ---------- S2: self-scan of hist0 (phase-0 rank walk) + hist1 accumulation.
__global__ __launch_bounds__(256) void k_s2(const float* __restrict__ x,
                                            int* __restrict__ state,
                                            const int* __restrict__ hist0,
                                            int* __restrict__ hist1) {
  int b     = blockIdx.x >> 7;
  int sub2  = blockIdx.x & 127;
  int itile = sub2 >> 4;
  int ktile = sub2 & 15;
  __shared__ float4 sxi[256];
  __shared__ float4 sxw[320];
  __shared__ int    sh[4096];
  __shared__ int    part[256];
  __shared__ int    s_sel0;

  const float4* xb = (const float4*)x + b*NPART;
  int ibase = itile*256;
  int k0 = ktile*64 + 1;
  sxi[threadIdx.x] = xb[ibase + threadIdx.x];
  for (int t = threadIdx.x; t < 320; t += 256)
    sxw[t] = xb[(ibase + k0 + t) & (NPART - 1)];
  for (int t = threadIdx.x; t < 4096; t += 256) sh[t] = 0;

  const int* h0 = hist0 + b*2048;
  int4 c0 = ((const int4*)h0)[threadIdx.x*2];
  int4 c1 = ((const int4*)h0)[threadIdx.x*2 + 1];
  int s = c0.x+c0.y+c0.z+c0.w + c1.x+c1.y+c1.z+c1.w;
  if (threadIdx.x == 0) s += NPART;   // diagonal zeros -> bin 0
  part[threadIdx.x] = s;
  __syncthreads();
  if (threadIdx.x == 0) {
    int r = KRANK, cum = 0, ch = 0;
    for (; ch < 256; ++ch) { if (cum + part[ch] > r) break; cum += part[ch]; }
    int4 d0 = ((const int4*)h0)[ch*2];
    int4 d1 = ((const int4*)h0)[ch*2 + 1];
    int cc[8] = {d0.x,d0.y,d0.z,d0.w,d1.x,d1.y,d1.z,d1.w};
    if (ch == 0) cc[0] += NPART;
    int q = 0;
    for (;; ++q) { if (cum + cc[q] > r) break; cum += cc[q]; }
    int bin = ch*8 + q;
    s_sel0 = bin;
    if (sub2 == 0) { state[b*2] = bin; state[b*2 + 1] = r - cum; }
  }
  __syncthreads();
  int sel0 = s_sel0;

  float4 xi = sxi[threadIdx.x];
#pragma unroll 4
  for (int kk = 0; kk < 64; ++kk) {
    int w = (ktile == 15 && kk == 63) ? 1 : 2;
    float4 xj = sxw[threadIdx.x + kk];
    float dx = xi.x - xj.x, dy = xi.y - xj.y;
    float dz = xi.z - xj.z, dw = xi.w - xj.w;
    float sq = dx*dx + dy*dy + dz*dz + dw*dw;
    unsigned bits = __float_as_uint(sq);
    if ((int)(bits >> 20) == sel0) atomicAdd(&sh[(bits >> 8) & 4095], w);
  }
  __syncthreads();
  int* hb = hist1 + b*4096;
  for (int t = threadIdx.x; t < 4096; t += 256) {
    int c = sh[t];
    if (c) atomicAdd(&hb[t], c);
  }
}

// ---------- S3: zero hist0; self-scan hist1 -> h; stein + RMSprop (R4 style).
// 1024 blocks, 16 particles/block, 16 threads/particle, 2-way ILP, global.
// MODE 0: first iter.  MODE 1: middle.  MODE 2: last (writes (B,N,5) out).
template <int MODE>
__global__ __launch_bounds__(256) void k_s3(const float* __restrict__ x,
                                            const float* __restrict__ g,
                                            const int* __restrict__ state,
                                            int* __restrict__ hist0,
                                            const int* __restrict__ hist1,
                                            float* __restrict__ stepb,
                                            float* __restrict__ xout,
                                            float* __restrict__ outp) {
  // zero hist0 (last read by S2, a previous kernel)
  if (threadIdx.x < 4)
    ((int4*)hist0)[blockIdx.x*4 + threadIdx.x] = make_int4(0, 0, 0, 0);

  int b = blockIdx.x >> 7;            // 128 blocks/batch
  __shared__ int   part[256];
  __shared__ float shp[2];            // -1/h, 2/h

  const int* h1 = hist1 + b*4096;
  int4 c0 = ((const int4*)h1)[threadIdx.x*4 + 0];
  int4 c1 = ((const int4*)h1)[threadIdx.x*4 + 1];
  int4 c2 = ((const int4*)h1)[threadIdx.x*4 + 2];
  int4 c3 = ((const int4*)h1)[threadIdx.x*4 + 3];
  int s = c0.x+c0.y+c0.z+c0.w + c1.x+c1.y+c1.z+c1.w
        + c2.x+c2.y+c2.z+c2.w + c3.x+c3.y+c3.z+c3.w;
  int sel0 = state[b*2];
  if (threadIdx.x == 0 && sel0 == 0) s += NPART;
  part[threadIdx.x] = s;
  __syncthreads();
  if (threadIdx.x == 0) {
    int r = state[b*2 + 1], cum = 0, ch = 0;
    for (; ch < 256; ++ch) { if (cum + part[ch] > r) break; cum += part[ch]; }
    int4 d0 = ((const int4*)h1)[ch*4 + 0];
    int4 d1 = ((const int4*)h1)[ch*4 + 1];
    int4 d2 = ((const int4*)h1)[ch*4 + 2];
    int4 d3 = ((const int4*)h1)[ch*4 + 3];
    int cc[16] = {d0.x,d0.y,d0.z,d0.w, d1.x,d1.y,d1.z,d1.w,
                  d2.x,d2.y,d2.z,d2.w, d3.x,d3.y,d3.z,d3.w};
    if (sel0 == 0 && ch == 0) cc[0] += NPART;
    int q = 0;
    for (;; ++q) { if (cum + cc[q] > r) break; cum += cc[q]; }
    int bin = ch*16 + q;
    // top 24 bits exact; low 8 -> midpoint (rel err <= 2^-16)
    unsigned mb = (((unsigned)sel0) << 20) | (((unsigned)bin) << 8) | 128u;
    float med = sqrtf(__uint_as_float(mb));
    float h = med * med / LOGN_F;
    shp[0] = -1.0f / h;
    shp[1] =  2.0f / h;
  }
  __syncthreads();
  float neginvh = shp[0];
  float two_h   = shp[1];

  int ip  = threadIdx.x >> 4;
  int sub = threadIdx.x & 15;
  int i = (blockIdx.x & 127)*16 + ip;
  const float4* xb = (const float4*)x + b*NPART;
  const float4* gb = (const float4*)g + b*NPART;
  float4 xi = xb[i];

  float4 Sd1 = make_float4(0.f,0.f,0.f,0.f), Sd2 = Sd1;
  float4 Sg1 = Sd1, Sg2 = Sd1;
#pragma unroll 4
  for (int c = 0; c < 64; ++c) {
    int j = sub + 16*c;
    float4 xj1 = xb[j];
    float4 xj2 = xb[j + 1024];
    float4 gj1 = gb[j];
    float4 gj2 = gb[j + 1024];
    float dx1 = xi.x-xj1.x, dy1 = xi.y-xj1.y, dz1 = xi.z-xj1.z, dw1 = xi.w-xj1.w;
    float dx2 = xi.x-xj2.x, dy2 = xi.y-xj2.y, dz2 = xi.z-xj2.z, dw2 = xi.w-xj2.w;
    float e1 = __expf((dx1*dx1 + dy1*dy1 + dz1*dz1 + dw1*dw1) * neginvh);
    float e2 = __expf((dx2*dx2 + dy2*dy2 + dz2*dz2 + dw2*dw2) * neginvh);
    Sd1.x += e1*dx1; Sd1.y += e1*dy1; Sd1.z += e1*dz1; Sd1.w += e1*dw1;
    Sd2.x += e2*dx2; Sd2.y += e2*dy2; Sd2.z += e2*dz2; Sd2.w += e2*dw2;
    Sg1.x += e1*gj1.x; Sg1.y += e1*gj1.y; Sg1.z += e1*gj1.z; Sg1.w += e1*gj1.w;
    Sg2.x += e2*gj2.x; Sg2.y += e2*gj2.y; Sg2.z += e2*gj2.z; Sg2.w += e2*gj2.w;
  }
  float4 Sd = make_float4(Sd1.x+Sd2.x, Sd1.y+Sd2.y, Sd1.z+Sd2.z, Sd1.w+Sd2.w);
  float4 Sg = make_float4(Sg1.x+Sg2.x, Sg1.y+Sg2.y, Sg1.z+Sg2.z, Sg1.w+Sg2.w);
#pragma unroll
  for (int d = 1; d < 16; d <<= 1) {
    Sd.x += __shfl_xor(Sd.x, d); Sd.y += __shfl_xor(Sd.y, d);
    Sd.z += __shfl_xor(Sd.z, d); Sd.w += __shfl_xor(Sd.w, d);
    Sg.x += __shfl_xor(Sg.x, d); Sg.y += __shfl_xor(Sg.y, d);
    Sg.z += __shfl_xor(Sg.z, d); Sg.w += __shfl_xor(Sg.w, d);
  }
  if (sub == 0) {
    const float invN = 1.0f / 2048.0f;
    float4 sv;
    sv.x = (Sg.x + two_h*Sd.x) * invN;
    sv.y = (Sg.y + two_h*Sd.y) * invN;
    sv.z = (Sg.z + two_h*Sd.z) * invN;
    sv.w = (Sg.w + two_h*Sd.w) * invN;
    float4 st;
    if (MODE == 0) {
      st = make_float4(0.1f*sv.x*sv.x, 0.1f*sv.y*sv.y,
                       0.1f*sv.z*sv.z, 0.1f*sv.w*sv.w);
    } else {
      st = ((float4*)stepb)[b*NPART + i];
      st.x = 0.9f*st.x + 0.1f*sv.x*sv.x;
      st.y = 0.9f*st.y + 0.1f*sv.y*sv.y;
      st.z = 0.9f*st.z + 0.1f*sv.z*sv.z;
      st.w = 0.9f*st.w + 0.1f*sv.w*sv.w;
    }
    float4 xn;
    xn.x = xi.x + 0.1f*sv.x / (sqrtf(st.x) + 1e-8f);
    xn.y = xi.y + 0.1f*sv.y / (sqrtf(st.y) + 1e-8f);
    xn.z = xi.z + 0.1f*sv.z / (sqrtf(st.z) + 1e-8f);
    xn.w = xi.w + 0.1f*sv.w / (sqrtf(st.w) + 1e-8f);
    if (MODE != 2) {
      ((float4*)stepb)[b*NPART + i] = st;
      ((float4*)xout)[b*NPART + i] = xn;
    } else {
      float* o = outp + (size_t)(b*NPART + i) * 5;
      o[0] = xn.x; o[1] = xn.y; o[2] = xn.z; o[3] = xn.w;
      o[4] = -LOGN_F;
    }
  }
}

extern "C" void kernel_launch(void* const* d_in, const int* in_sizes, int n_in,
                              void* d_out, int out_size, void* d_ws, size_t ws_size,
                              hipStream_t stream) {
  const float* prev  = (const float*)d_in[0];   // (8,2048,4)
  const float* obs   = (const float*)d_in[1];   // (8,4)
  const float* noise = (const float*)d_in[2];   // (8,2048,4)
  float* out = (float*)d_out;                   // (8,2048,5)

  float* ws = (float*)d_ws;
  float* xA    = ws;
  float* xB    = xA + 65536;
  float* gbuf  = xB + 65536;
  float* stepb = gbuf + 65536;
  float* apb   = stepb + 65536;
  int*   state = (int*)(apb + 65536);       // 16 ints
  int*   hist0 = state + 16;                // 8*2048 ints
  int*   hist1 = hist0 + 8*2048;            // 8*4096 ints

  k_init<<<64, 256, 0, stream>>>(prev, noise, xA, apb, hist0);

  float* xc = xA;
  float* xn = xB;
  for (int it = 0; it < 3; ++it) {
    k_s1<<<2048, 256, 0, stream>>>(xc, apb, obs, gbuf, hist0, hist1);
    k_s2<<<1024, 256, 0, stream>>>(xc, state, hist0, hist1);
    if (it == 0) {
      k_s3<0><<<1024, 256, 0, stream>>>(xc, gbuf, state, hist0, hist1, stepb, xn, nullptr);
    } else if (it == 1) {
      k_s3<1><<<1024, 256, 0, stream>>>(xc, gbuf, state, hist0, hist1, stepb, xn, nullptr);
    } else {
      k_s3<2><<<1024, 256, 0, stream>>>(xc, gbuf, state, hist0, hist1, stepb, nullptr, out);
    }
    float* t = xc; xc = xn; xn = t;
  }
}

// Round 14
// 350.001 us; speedup vs baseline: 1.0540x; 1.0540x over previous
//
#include <hip/hip_runtime.h>
#include <math.h>

// SVPF step: B=8, N=2048, D=4, fp32.  3 SVGD iterations.
// log_weight output channel is exactly -log(2048) (log_post cancels).
//
// R14 changes vs R13 (diagnosis: k_s3 VALUBusy 31% / Occupancy 33% with
// VGPR=36, no spill, no conflicts -> latency-bound and GRID-capped:
// 1024 blocks x 4 waves / 256 CU = 16 waves/CU = half of capacity):
//  - stein: 2048 blocks, 8 particles/block, 32 lanes/particle (2-way ILP,
//    32-iter loop).  Occupancy cap 16 -> 32 waves/CU.
//  - grad: same 32-lane/8-particle shape; s1 = 3072 blocks, role by %3
//    (2 grad : 1 hist0) to keep per-CU role mix.
//  - s2 and hist0 bodies unchanged (attribution).
//
// ws layout (floats):
//   xA[65536] xB[65536] g[65536] step[65536] ap[65536]
//   state[16 ints] hist0[8*2048 ints] hist1[8*4096 ints]

#define NPART 2048
#define KRANK 2097151               // (2048*2048-1)/2, lower-median rank
#define LOGN_F 7.6246189861593985f  // log(2048)
#define A_C 0.9f

// ---------- init: x0 = A*prev + noise; ap = A*prev; zero hist0+hist1
__global__ __launch_bounds__(256) void k_init(const float* __restrict__ prev,
                                              const float* __restrict__ noise,
                                              float* __restrict__ x0,
                                              float* __restrict__ apb,
                                              int* __restrict__ hists) {
  int idx = blockIdx.x * 256 + threadIdx.x;   // 0..16383 (B*N)
  float4 p  = ((const float4*)prev)[idx];
  float4 nz = ((const float4*)noise)[idx];
  float4 ap = make_float4(A_C*p.x, A_C*p.y, A_C*p.z, A_C*p.w);
  ((float4*)x0)[idx]  = make_float4(ap.x+nz.x, ap.y+nz.y, ap.z+nz.z, ap.w+nz.w);
  ((float4*)apb)[idx] = ap;
  if (idx < 12288) ((int4*)hists)[idx] = make_int4(0, 0, 0, 0);  // 49152 ints
}

// ---------- S1: 3072 blocks.  blockIdx%3 in {0,1}: grad; ==2: hist0.
// grad: 32 threads/particle, 8 particles/block, 2048 blocks.
// hist0: unchanged body, 1024 blocks.  Also zeroes hist1.
__global__ __launch_bounds__(256) void k_s1(const float* __restrict__ x,
                                            const float* __restrict__ apb,
                                            const float* __restrict__ obs,
                                            float* __restrict__ g,
                                            int* __restrict__ hist0,
                                            int* __restrict__ hist1) {
  // zero hist1: 8192 int4 over the first 2048 blocks x 4
  if (threadIdx.x < 4 && blockIdx.x < 2048)
    ((int4*)hist1)[blockIdx.x*4 + threadIdx.x] = make_int4(0, 0, 0, 0);
  int m = blockIdx.x % 3;
  int base = blockIdx.x / 3;

  if (m != 2) {
    // ---- grad: 32 lanes/particle ----
    int grad_id = base*2 + m;               // 0..2047
    int b   = grad_id >> 8;                 // 256 blocks/batch
    int ip  = threadIdx.x >> 5;             // 8 particles/block
    int sub = threadIdx.x & 31;
    int i = (grad_id & 255)*8 + ip;
    const float4* ab = (const float4*)apb + b*NPART;
    float4 xi = ((const float4*)x)[b*NPART + i];

    float sum1 = 0.f, sum2 = 0.f;
    float4 acc1 = make_float4(0.f,0.f,0.f,0.f);
    float4 acc2 = make_float4(0.f,0.f,0.f,0.f);
#pragma unroll 4
    for (int c = 0; c < 32; ++c) {
      int j = sub + 32*c;
      float4 a1 = ab[j];
      float4 a2 = ab[j + 1024];
      float dx1 = xi.x-a1.x, dy1 = xi.y-a1.y, dz1 = xi.z-a1.z, dw1 = xi.w-a1.w;
      float dx2 = xi.x-a2.x, dy2 = xi.y-a2.y, dz2 = xi.z-a2.z, dw2 = xi.w-a2.w;
      float e1 = __expf(-0.5f*(dx1*dx1 + dy1*dy1 + dz1*dz1 + dw1*dw1));
      float e2 = __expf(-0.5f*(dx2*dx2 + dy2*dy2 + dz2*dz2 + dw2*dw2));
      sum1 += e1; sum2 += e2;
      acc1.x += e1*a1.x; acc1.y += e1*a1.y; acc1.z += e1*a1.z; acc1.w += e1*a1.w;
      acc2.x += e2*a2.x; acc2.y += e2*a2.y; acc2.z += e2*a2.z; acc2.w += e2*a2.w;
    }
    float sum = sum1 + sum2;
    float4 acc = make_float4(acc1.x+acc2.x, acc1.y+acc2.y,
                             acc1.z+acc2.z, acc1.w+acc2.w);
#pragma unroll
    for (int d = 1; d < 32; d <<= 1) {
      sum   += __shfl_xor(sum, d);
      acc.x += __shfl_xor(acc.x, d);
      acc.y += __shfl_xor(acc.y, d);
      acc.z += __shfl_xor(acc.z, d);
      acc.w += __shfl_xor(acc.w, d);
    }
    if (sub == 0) {
      float inv = 1.0f / sum;
      float4 ob = ((const float4*)obs)[b];
      float4 gg;
      gg.x = acc.x*inv + ob.x - 2.0f*xi.x;
      gg.y = acc.y*inv + ob.y - 2.0f*xi.y;
      gg.z = acc.z*inv + ob.z - 2.0f*xi.z;
      gg.w = acc.w*inv + ob.w - 2.0f*xi.w;
      ((float4*)g)[b*NPART + i] = gg;
    }
  } else {
    // ---- hist0: LDS-staged, 2-copy histogram (unchanged body) ----
    int id    = base;                 // 0..1023
    int b     = id >> 7;
    int sub2  = id & 127;
    int itile = sub2 >> 4;            // 8 i-tiles of 256
    int ktile = sub2 & 15;            // 16 k-tiles of 64
    __shared__ float4 sxi[256];
    __shared__ float4 sxw[320];
    __shared__ int    sh[2*2049];

    const float4* xb = (const float4*)x + b*NPART;
    int ibase = itile*256;
    int k0 = ktile*64 + 1;
    sxi[threadIdx.x] = xb[ibase + threadIdx.x];
    for (int t = threadIdx.x; t < 320; t += 256)
      sxw[t] = xb[(ibase + k0 + t) & (NPART - 1)];
    for (int t = threadIdx.x; t < 2*2049; t += 256) sh[t] = 0;
    __syncthreads();

    float4 xi = sxi[threadIdx.x];
    int cofs = (threadIdx.x & 1) * 2049;
#pragma unroll 4
    for (int kk = 0; kk < 64; ++kk) {
      int w = (ktile == 15 && kk == 63) ? 1 : 2;   // wave-uniform
      float4 xj = sxw[threadIdx.x + kk];
      float dx = xi.x - xj.x, dy = xi.y - xj.y;
      float dz = xi.z - xj.z, dw = xi.w - xj.w;
      float sq = dx*dx + dy*dy + dz*dz + dw*dw;    // >= 0
      atomicAdd(&sh[cofs + (__float_as_uint(sq) >> 20)], w);
    }
    __syncthreads();
    int* hb = hist0 + b*2048;
    for (int t = threadIdx.x; t < 2048; t += 256) {
      int c = sh[t] + sh[t + 2049];
      if (c) atomicAdd(&hb[t], c);
    }
  }
}

// ---------- S2: self-scan of hist0 (phase-0 rank walk) + hist1 accumulation.
__global__ __launch_bounds__(256) void k_s2(const float* __restrict__ x,
                                            int* __restrict__ state,
                                            const int* __restrict__ hist0,
                                            int* __restrict__ hist1) {
  int b     = blockIdx.x >> 7;
  int sub2  = blockIdx.x & 127;
  int itile = sub2 >> 4;
  int ktile = sub2 & 15;
  __shared__ float4 sxi[256];
  __shared__ float4 sxw[320];
  __shared__ int    sh[4096];
  __shared__ int    part[256];
  __shared__ int    s_sel0;

  const float4* xb = (const float4*)x + b*NPART;
  int ibase = itile*256;
  int k0 = ktile*64 + 1;
  sxi[threadIdx.x] = xb[ibase + threadIdx.x];
  for (int t = threadIdx.x; t < 320; t += 256)
    sxw[t] = xb[(ibase + k0 + t) & (NPART - 1)];
  for (int t = threadIdx.x; t < 4096; t += 256) sh[t] = 0;

  const int* h0 = hist0 + b*2048;
  int4 c0 = ((const int4*)h0)[threadIdx.x*2];
  int4 c1 = ((const int4*)h0)[threadIdx.x*2 + 1];
  int s = c0.x+c0.y+c0.z+c0.w + c1.x+c1.y+c1.z+c1.w;
  if (threadIdx.x == 0) s += NPART;   // diagonal zeros -> bin 0
  part[threadIdx.x] = s;
  __syncthreads();
  if (threadIdx.x == 0) {
    int r = KRANK, cum = 0, ch = 0;
    for (; ch < 256; ++ch) { if (cum + part[ch] > r) break; cum += part[ch]; }
    int4 d0 = ((const int4*)h0)[ch*2];
    int4 d1 = ((const int4*)h0)[ch*2 + 1];
    int cc[8] = {d0.x,d0.y,d0.z,d0.w,d1.x,d1.y,d1.z,d1.w};
    if (ch == 0) cc[0] += NPART;
    int q = 0;
    for (;; ++q) { if (cum + cc[q] > r) break; cum += cc[q]; }
    int bin = ch*8 + q;
    s_sel0 = bin;
    if (sub2 == 0) { state[b*2] = bin; state[b*2 + 1] = r - cum; }
  }
  __syncthreads();
  int sel0 = s_sel0;

  float4 xi = sxi[threadIdx.x];
#pragma unroll 4
  for (int kk = 0; kk < 64; ++kk) {
    int w = (ktile == 15 && kk == 63) ? 1 : 2;
    float4 xj = sxw[threadIdx.x + kk];
    float dx = xi.x - xj.x, dy = xi.y - xj.y;
    float dz = xi.z - xj.z, dw = xi.w - xj.w;
    float sq = dx*dx + dy*dy + dz*dz + dw*dw;
    unsigned bits = __float_as_uint(sq);
    if ((int)(bits >> 20) == sel0) atomicAdd(&sh[(bits >> 8) & 4095], w);
  }
  __syncthreads();
  int* hb = hist1 + b*4096;
  for (int t = threadIdx.x; t < 4096; t += 256) {
    int c = sh[t];
    if (c) atomicAdd(&hb[t], c);
  }
}

// ---------- S3: zero hist0; self-scan hist1 -> h; stein + RMSprop.
// 2048 blocks, 8 particles/block, 32 threads/particle, 2-way ILP, global.
// MODE 0: first iter.  MODE 1: middle.  MODE 2: last (writes (B,N,5) out).
template <int MODE>
__global__ __launch_bounds__(256) void k_s3(const float* __restrict__ x,
                                            const float* __restrict__ g,
                                            const int* __restrict__ state,
                                            int* __restrict__ hist0,
                                            const int* __restrict__ hist1,
                                            float* __restrict__ stepb,
                                            float* __restrict__ xout,
                                            float* __restrict__ outp) {
  // zero hist0: 4096 int4 over 2048 blocks x 2
  if (threadIdx.x < 2)
    ((int4*)hist0)[blockIdx.x*2 + threadIdx.x] = make_int4(0, 0, 0, 0);

  int b = blockIdx.x >> 8;            // 256 blocks/batch
  __shared__ int   part[256];
  __shared__ float shp[2];            // -1/h, 2/h

  const int* h1 = hist1 + b*4096;
  int4 c0 = ((const int4*)h1)[threadIdx.x*4 + 0];
  int4 c1 = ((const int4*)h1)[threadIdx.x*4 + 1];
  int4 c2 = ((const int4*)h1)[threadIdx.x*4 + 2];
  int4 c3 = ((const int4*)h1)[threadIdx.x*4 + 3];
  int s = c0.x+c0.y+c0.z+c0.w + c1.x+c1.y+c1.z+c1.w
        + c2.x+c2.y+c2.z+c2.w + c3.x+c3.y+c3.z+c3.w;
  int sel0 = state[b*2];
  if (threadIdx.x == 0 && sel0 == 0) s += NPART;
  part[threadIdx.x] = s;
  __syncthreads();
  if (threadIdx.x == 0) {
    int r = state[b*2 + 1], cum = 0, ch = 0;
    for (; ch < 256; ++ch) { if (cum + part[ch] > r) break; cum += part[ch]; }
    int4 d0 = ((const int4*)h1)[ch*4 + 0];
    int4 d1 = ((const int4*)h1)[ch*4 + 1];
    int4 d2 = ((const int4*)h1)[ch*4 + 2];
    int4 d3 = ((const int4*)h1)[ch*4 + 3];
    int cc[16] = {d0.x,d0.y,d0.z,d0.w, d1.x,d1.y,d1.z,d1.w,
                  d2.x,d2.y,d2.z,d2.w, d3.x,d3.y,d3.z,d3.w};
    if (sel0 == 0 && ch == 0) cc[0] += NPART;
    int q = 0;
    for (;; ++q) { if (cum + cc[q] > r) break; cum += cc[q]; }
    int bin = ch*16 + q;
    // top 24 bits exact; low 8 -> midpoint (rel err <= 2^-16)
    unsigned mb = (((unsigned)sel0) << 20) | (((unsigned)bin) << 8) | 128u;
    float med = sqrtf(__uint_as_float(mb));
    float h = med * med / LOGN_F;
    shp[0] = -1.0f / h;
    shp[1] =  2.0f / h;
  }
  __syncthreads();
  float neginvh = shp[0];
  float two_h   = shp[1];

  int ip  = threadIdx.x >> 5;         // 8 particles/block
  int sub = threadIdx.x & 31;
  int i = (blockIdx.x & 255)*8 + ip;
  const float4* xb = (const float4*)x + b*NPART;
  const float4* gb = (const float4*)g + b*NPART;
  float4 xi = xb[i];

  float4 Sd1 = make_float4(0.f,0.f,0.f,0.f), Sd2 = Sd1;
  float4 Sg1 = Sd1, Sg2 = Sd1;
#pragma unroll 4
  for (int c = 0; c < 32; ++c) {
    int j = sub + 32*c;
    float4 xj1 = xb[j];
    float4 xj2 = xb[j + 1024];
    float4 gj1 = gb[j];
    float4 gj2 = gb[j + 1024];
    float dx1 = xi.x-xj1.x, dy1 = xi.y-xj1.y, dz1 = xi.z-xj1.z, dw1 = xi.w-xj1.w;
    float dx2 = xi.x-xj2.x, dy2 = xi.y-xj2.y, dz2 = xi.z-xj2.z, dw2 = xi.w-xj2.w;
    float e1 = __expf((dx1*dx1 + dy1*dy1 + dz1*dz1 + dw1*dw1) * neginvh);
    float e2 = __expf((dx2*dx2 + dy2*dy2 + dz2*dz2 + dw2*dw2) * neginvh);
    Sd1.x += e1*dx1; Sd1.y += e1*dy1; Sd1.z += e1*dz1; Sd1.w += e1*dw1;
    Sd2.x += e2*dx2; Sd2.y += e2*dy2; Sd2.z += e2*dz2; Sd2.w += e2*dw2;
    Sg1.x += e1*gj1.x; Sg1.y += e1*gj1.y; Sg1.z += e1*gj1.z; Sg1.w += e1*gj1.w;
    Sg2.x += e2*gj2.x; Sg2.y += e2*gj2.y; Sg2.z += e2*gj2.z; Sg2.w += e2*gj2.w;
  }
  float4 Sd = make_float4(Sd1.x+Sd2.x, Sd1.y+Sd2.y, Sd1.z+Sd2.z, Sd1.w+Sd2.w);
  float4 Sg = make_float4(Sg1.x+Sg2.x, Sg1.y+Sg2.y, Sg1.z+Sg2.z, Sg1.w+Sg2.w);
#pragma unroll
  for (int d = 1; d < 32; d <<= 1) {
    Sd.x += __shfl_xor(Sd.x, d); Sd.y += __shfl_xor(Sd.y, d);
    Sd.z += __shfl_xor(Sd.z, d); Sd.w += __shfl_xor(Sd.w, d);
    Sg.x += __shfl_xor(Sg.x, d); Sg.y += __shfl_xor(Sg.y, d);
    Sg.z += __shfl_xor(Sg.z, d); Sg.w += __shfl_xor(Sg.w, d);
  }
  if (sub == 0) {
    const float invN = 1.0f / 2048.0f;
    float4 sv;
    sv.x = (Sg.x + two_h*Sd.x) * invN;
    sv.y = (Sg.y + two_h*Sd.y) * invN;
    sv.z = (Sg.z + two_h*Sd.z) * invN;
    sv.w = (Sg.w + two_h*Sd.w) * invN;
    float4 st;
    if (MODE == 0) {
      st = make_float4(0.1f*sv.x*sv.x, 0.1f*sv.y*sv.y,
                       0.1f*sv.z*sv.z, 0.1f*sv.w*sv.w);
    } else {
      st = ((float4*)stepb)[b*NPART + i];
      st.x = 0.9f*st.x + 0.1f*sv.x*sv.x;
      st.y = 0.9f*st.y + 0.1f*sv.y*sv.y;
      st.z = 0.9f*st.z + 0.1f*sv.z*sv.z;
      st.w = 0.9f*st.w + 0.1f*sv.w*sv.w;
    }
    float4 xn;
    xn.x = xi.x + 0.1f*sv.x / (sqrtf(st.x) + 1e-8f);
    xn.y = xi.y + 0.1f*sv.y / (sqrtf(st.y) + 1e-8f);
    xn.z = xi.z + 0.1f*sv.z / (sqrtf(st.z) + 1e-8f);
    xn.w = xi.w + 0.1f*sv.w / (sqrtf(st.w) + 1e-8f);
    if (MODE != 2) {
      ((float4*)stepb)[b*NPART + i] = st;
      ((float4*)xout)[b*NPART + i] = xn;
    } else {
      float* o = outp + (size_t)(b*NPART + i) * 5;
      o[0] = xn.x; o[1] = xn.y; o[2] = xn.z; o[3] = xn.w;
      o[4] = -LOGN_F;
    }
  }
}

extern "C" void kernel_launch(void* const* d_in, const int* in_sizes, int n_in,
                              void* d_out, int out_size, void* d_ws, size_t ws_size,
                              hipStream_t stream) {
  const float* prev  = (const float*)d_in[0];   // (8,2048,4)
  const float* obs   = (const float*)d_in[1];   // (8,4)
  const float* noise = (const float*)d_in[2];   // (8,2048,4)
  float* out = (float*)d_out;                   // (8,2048,5)

  float* ws = (float*)d_ws;
  float* xA    = ws;
  float* xB    = xA + 65536;
  float* gbuf  = xB + 65536;
  float* stepb = gbuf + 65536;
  float* apb   = stepb + 65536;
  int*   state = (int*)(apb + 65536);       // 16 ints
  int*   hist0 = state + 16;                // 8*2048 ints
  int*   hist1 = hist0 + 8*2048;            // 8*4096 ints

  k_init<<<64, 256, 0, stream>>>(prev, noise, xA, apb, hist0);

  float* xc = xA;
  float* xn = xB;
  for (int it = 0; it < 3; ++it) {
    k_s1<<<3072, 256, 0, stream>>>(xc, apb, obs, gbuf, hist0, hist1);
    k_s2<<<1024, 256, 0, stream>>>(xc, state, hist0, hist1);
    if (it == 0) {
      k_s3<0><<<2048, 256, 0, stream>>>(xc, gbuf, state, hist0, hist1, stepb, xn, nullptr);
    } else if (it == 1) {
      k_s3<1><<<2048, 256, 0, stream>>>(xc, gbuf, state, hist0, hist1, stepb, xn, nullptr);
    } else {
      k_s3<2><<<2048, 256, 0, stream>>>(xc, gbuf, state, hist0, hist1, stepb, nullptr, out);
    }
    float* t = xc; xc = xn; xn = t;
  }
}